// Round 6
// baseline (150.393 us; speedup 1.0000x reference)
//
#include <hip/hip_runtime.h>
#include <math.h>
#include <stdint.h>

#define NH     12
#define DH     64
#define WIN    32
#define SEQL   1024
#define BSZ    2
#define NW     (SEQL / WIN)       // 32
#define DMODEL 768
#define NCOL   (5 * NH * DH)      // 3840

typedef __attribute__((ext_vector_type(4))) float f32x4;
typedef __attribute__((ext_vector_type(8))) short bf16x8;
typedef unsigned short u16;

static __device__ __forceinline__ u16 f2bf(float f) {
  union { float f; unsigned u; } v; v.f = f;
  unsigned r = v.u + 0x7fffu + ((v.u >> 16) & 1u);
  return (u16)(r >> 16);
}
static __device__ __forceinline__ float bf2f(u16 u) {
  union { unsigned u; float f; } v; v.u = ((unsigned)u) << 16;
  return v.f;
}
// D[15:0]=bf16(lo), D[31:16]=bf16(hi) — hw packed convert (RNE)
static __device__ __forceinline__ unsigned cvt_pk_bf16(float lo, float hi) {
  unsigned p;
  asm("v_cvt_pk_bf16_f32 %0, %1, %2" : "=v"(p) : "v"(lo), "v"(hi));
  return p;
}

typedef const __attribute__((address_space(1))) unsigned int* as1_cu32;
typedef __attribute__((address_space(3))) unsigned int* as3_u32;
static __device__ __forceinline__ void gload_lds16(const void* g, void* l) {
  __builtin_amdgcn_global_load_lds(
      reinterpret_cast<as1_cu32>(reinterpret_cast<uintptr_t>(g)),
      reinterpret_cast<as3_u32>(reinterpret_cast<uintptr_t>(l)), 16, 0, 0);
}

// ---------------------------------------------------------------------------
// Fused prep: [0,1536) cvt x->bf16; [1536,2256) transpose W_abcde;
// [2256,2400) transpose W_O.
// ---------------------------------------------------------------------------
__global__ __launch_bounds__(256)
void prep_kernel(const float* __restrict__ x, const float* __restrict__ W,
                 const float* __restrict__ WO, u16* __restrict__ xb,
                 u16* __restrict__ Wt, u16* __restrict__ WOt) {
  __shared__ u16 tile[64][68];
  const int bid = blockIdx.x;
  const int tid = threadIdx.x;

  if (bid < 1536) {                      // ---- cvt x (2048*768 elems, x4)
    const int i = bid * 256 + tid;
    const float4 v = reinterpret_cast<const float4*>(x)[i];
    ushort4 o;
    o.x = f2bf(v.x); o.y = f2bf(v.y); o.z = f2bf(v.z); o.w = f2bf(v.w);
    reinterpret_cast<ushort4*>(xb)[i] = o;
    return;
  }

  const float* S; u16* D; int K, N, n0, k0;
  if (bid < 2256) {                      // ---- W_abcde [768][3840] -> [3840][768]
    const int b = bid - 1536;
    S = W; D = Wt; K = DMODEL; N = NCOL;
    n0 = (b % 60) * 64; k0 = (b / 60) * 64;
  } else {                               // ---- W_O [768][768] -> [768][768]
    const int b = bid - 2256;
    S = WO; D = WOt; K = DMODEL; N = NH * DH;
    n0 = (b % 12) * 64; k0 = (b / 12) * 64;
  }
#pragma unroll
  for (int pass = 0; pass < 4; ++pass) {
    const int r = pass * 16 + (tid >> 4);
    const int c = (tid & 15) << 2;
    const float4 v = *reinterpret_cast<const float4*>(&S[(size_t)(k0 + r) * N + n0 + c]);
    tile[c + 0][r] = f2bf(v.x); tile[c + 1][r] = f2bf(v.y);
    tile[c + 2][r] = f2bf(v.z); tile[c + 3][r] = f2bf(v.w);
  }
  __syncthreads();
#pragma unroll
  for (int pass = 0; pass < 4; ++pass) {
    const int rn = pass * 16 + (tid >> 4);
    const int ck = (tid & 15) << 2;
    ushort4 o;
    o.x = tile[rn][ck + 0]; o.y = tile[rn][ck + 1];
    o.z = tile[rn][ck + 2]; o.w = tile[rn][ck + 3];
    *reinterpret_cast<ushort4*>(&D[(size_t)(n0 + rn) * K + k0 + ck]) = o;
  }
}

// ---------------------------------------------------------------------------
// bf16 MFMA GEMM, 2-phase double-buffered (T3-minimum): issue next-tile
// global_load_lds BEFORE current-tile ds_read+MFMA; one vmcnt-drain barrier
// per K-step (the __syncthreads). Loads fly under the whole compute phase.
// ---------------------------------------------------------------------------
template<int BM, int BN, int WAVES_M, int WAVES_N, bool OUT_BF16>
__global__ __launch_bounds__(256)
void gemm_mfma_kernel(const u16* __restrict__ A, const u16* __restrict__ Bt,
                      const float* __restrict__ bias, void* __restrict__ Cout,
                      int M, int N, int K) {
  constexpr int BK = 64;
  constexpr int MT = BM / (16 * WAVES_M);
  constexpr int NT = BN / (16 * WAVES_N);
  constexpr int CHA = BM / 8;
  constexpr int CHB = BN / 8;
  __shared__ __align__(16) u16 As[2][BM * BK];
  __shared__ __align__(16) u16 Bs[2][BN * BK];

  const int tid  = threadIdx.x;
  const int w    = tid >> 6;
  const int lane = tid & 63;
  const int m16  = lane & 15;
  const int g    = lane >> 4;
  const int wr   = w / WAVES_N;
  const int wc   = w % WAVES_N;
  const int bm   = blockIdx.y * BM;
  const int bn   = blockIdx.x * BN;

  const int srow   = lane >> 3;
  const int srcCol = ((lane & 7) ^ srow) << 3;

  auto stage = [&](int buf, int k0) {
#pragma unroll
    for (int c = 0; c < CHA / 4; ++c) {
      const int ch = w * (CHA / 4) + c;
      const int r  = ch * 8 + srow;
      gload_lds16(A + (size_t)(bm + r) * K + k0 + srcCol, &As[buf][ch * 512]);
    }
#pragma unroll
    for (int c = 0; c < CHB / 4; ++c) {
      const int ch = w * (CHB / 4) + c;
      const int r  = ch * 8 + srow;
      gload_lds16(Bt + (size_t)(bn + r) * K + k0 + srcCol, &Bs[buf][ch * 512]);
    }
  };

  f32x4 acc[MT][NT];
#pragma unroll
  for (int i = 0; i < MT; ++i)
#pragma unroll
    for (int j = 0; j < NT; ++j) {
      f32x4 z = {0.f, 0.f, 0.f, 0.f};
      acc[i][j] = z;
    }

  stage(0, 0);
  __syncthreads();           // drains vmcnt(0): buf0 ready

  int cur = 0;
  for (int k0 = 0; k0 < K; k0 += BK) {
    const int nk = k0 + BK;
    if (nk < K) stage(cur ^ 1, nk);    // issue next-tile loads FIRST

#pragma unroll
    for (int kk = 0; kk < 2; ++kk) {
      const int cs = (((kk << 2) + g) ^ (m16 & 7)) << 3;
      bf16x8 af[MT], bf[NT];
#pragma unroll
      for (int i = 0; i < MT; ++i) {
        const int r = wr * (16 * MT) + i * 16 + m16;
        af[i] = *reinterpret_cast<const bf16x8*>(&As[cur][r * 64 + cs]);
      }
#pragma unroll
      for (int j = 0; j < NT; ++j) {
        const int r = wc * (16 * NT) + j * 16 + m16;
        bf[j] = *reinterpret_cast<const bf16x8*>(&Bs[cur][r * 64 + cs]);
      }
#pragma unroll
      for (int i = 0; i < MT; ++i)
#pragma unroll
        for (int j = 0; j < NT; ++j)
          acc[i][j] = __builtin_amdgcn_mfma_f32_16x16x32_bf16(af[i], bf[j], acc[i][j], 0, 0, 0);
    }
    __syncthreads();         // next buf landed; all waves done reading cur
    cur ^= 1;
  }

#pragma unroll
  for (int i = 0; i < MT; ++i) {
#pragma unroll
    for (int j = 0; j < NT; ++j) {
      const int col = bn + wc * 16 * NT + j * 16 + m16;
      const float bcol = bias[col];
#pragma unroll
      for (int rr = 0; rr < 4; ++rr) {
        const int row = bm + wr * 16 * MT + i * 16 + g * 4 + rr;
        const float v = acc[i][j][rr] + bcol;
        if (OUT_BF16)
          reinterpret_cast<u16*>(Cout)[(size_t)row * N + col] = f2bf(v);
        else
          reinterpret_cast<float*>(Cout)[(size_t)row * N + col] = v;
      }
    }
  }
}

// ---------------------------------------------------------------------------
// MFMA trittention v4: v3 + next-query c-row prefetch + qp tree-add (breaks
// the 16-deep serial accumulation chain into 1 chained add per tile).
// ---------------------------------------------------------------------------
__global__ __launch_bounds__(512, 3)
void attn_mfma_kernel(const u16* __restrict__ Y, u16* __restrict__ Z) {
  __shared__ __align__(16) u16 DET[64][136];  // [d][0..63]=D^T, [64..127]=E^T
  __shared__ __align__(16) u16 RQ[32][136];   // [i][0..63]=r[j], [64..127]=q[k]
  __shared__ float tot_lds[32];

  const int n  = blockIdx.x;
  const int bh = blockIdx.y;
  const int bi = bh / NH;
  const int h  = bh % NH;
  const int tid  = threadIdx.x;
  const int wv   = tid >> 6;      // 0..7
  const int lane = tid & 63;
  const int m16  = lane & 15;
  const int g    = lane >> 4;
  const int g4   = g << 2;
  const u16* Yb = Y + (size_t)bi * SEQL * NCOL;

  // ---- stage D^T / E^T: wave wv writes dims [wv*8, wv*8+8), lane = j
  {
    const int j  = lane;
    const int r8 = wv * 8;
    const int t  = n * WIN - WIN + j;
    if (t >= 0) {
      const bf16x8 dv = *reinterpret_cast<const bf16x8*>(
          Yb + (size_t)t * NCOL + (3 * NH + h) * DH + r8);
      const bf16x8 ev = *reinterpret_cast<const bf16x8*>(
          Yb + (size_t)t * NCOL + (4 * NH + h) * DH + r8);
#pragma unroll
      for (int e = 0; e < 8; ++e) {
        DET[r8 + e][j]      = (u16)dv[e];
        DET[r8 + e][64 + j] = (u16)ev[e];
      }
    } else {
#pragma unroll
      for (int e = 0; e < 8; ++e) {
        DET[r8 + e][j] = 0;
        DET[r8 + e][64 + j] = 0;
      }
    }
  }

  // ---- preload A-fragments and b rows (bf16 regs)
  bf16x8 afr[4][2], bfrb[4][2];
#pragma unroll
  for (int jt = 0; jt < 4; ++jt) {
    const int t = n * WIN - WIN + jt * 16 + m16;
#pragma unroll
    for (int ks = 0; ks < 2; ++ks) {
      if (n == 0 && jt < 2) {
        bf16x8 z = {0, 0, 0, 0, 0, 0, 0, 0};
        afr[jt][ks] = z;
        bfrb[jt][ks] = z;
      } else {
        afr[jt][ks] = *reinterpret_cast<const bf16x8*>(
            Yb + (size_t)t * NCOL + h * DH + ks * 32 + g * 8);
        bfrb[jt][ks] = *reinterpret_cast<const bf16x8*>(
            Yb + (size_t)t * NCOL + (NH + h) * DH + ks * 32 + g * 8);
      }
    }
  }

  const float K2 = 0.015625f * 1.44269504088896341f;  // log2(e)/64
  const u16* crow_base = Yb + (size_t)(n * WIN) * NCOL + (2 * NH + h) * DH;

  // prefetch first query's c-row
  bf16x8 craw0 = *reinterpret_cast<const bf16x8*>(
      crow_base + (size_t)(wv * 4) * NCOL + g * 8);
  bf16x8 craw1 = *reinterpret_cast<const bf16x8*>(
      crow_base + (size_t)(wv * 4) * NCOL + 32 + g * 8);

  for (int ii = 0; ii < 4; ++ii) {
    const int i = wv * 4 + ii;

    // cf = c * K2 (fp32), consume prefetched craw
    float cf[2][8];
#pragma unroll
    for (int e = 0; e < 8; ++e) {
      cf[0][e] = bf2f((u16)craw0[e]) * K2;
      cf[1][e] = bf2f((u16)craw1[e]) * K2;
    }
    // issue next query's c-row load early (hides L2 latency under compute)
    if (ii < 3) {
      const u16* cpn = crow_base + (size_t)(i + 1) * NCOL;
      craw0 = *reinterpret_cast<const bf16x8*>(cpn + g * 8);
      craw1 = *reinterpret_cast<const bf16x8*>(cpn + 32 + g * 8);
    }

    f32x4 acc[4][4];
#pragma unroll
    for (int kt = 0; kt < 4; ++kt)
#pragma unroll
      for (int jt = 0; jt <= kt; ++jt) {
        f32x4 z = {0.f, 0.f, 0.f, 0.f};
        acc[jt][kt] = z;
      }

    // S_i*K2 = A @ (c_i*K2 * B)^T : only jt<=kt tiles (20 MFMAs)
#pragma unroll
    for (int ks = 0; ks < 2; ++ks) {
#pragma unroll
      for (int kt = 0; kt < 4; ++kt) {
        bf16x8 vf;
#pragma unroll
        for (int e = 0; e < 8; e += 2) {
          const float lo = bf2f((u16)bfrb[kt][ks][e])     * cf[ks][e];
          const float hi = bf2f((u16)bfrb[kt][ks][e + 1]) * cf[ks][e + 1];
          reinterpret_cast<unsigned*>(&vf)[e >> 1] = cvt_pk_bf16(lo, hi);
        }
#pragma unroll
        for (int jt = 0; jt <= kt; ++jt)
          acc[jt][kt] = __builtin_amdgcn_mfma_f32_16x16x32_bf16(afr[jt][ks], vf, acc[jt][kt], 0, 0, 0);
      }
    }

    // ---- exp + masked marginal partials (upper-triangle tiles only)
    float rp[16], qp[4];
#pragma unroll
    for (int u = 0; u < 16; ++u) rp[u] = 0.f;
#pragma unroll
    for (int u = 0; u < 4; ++u) qp[u] = 0.f;
#pragma unroll
    for (int kt = 0; kt < 4; ++kt) {
      const bool ck = (kt < 2) ? true : (kt * 16 + m16 <= i + 32);
#pragma unroll
      for (int jt = 0; jt <= kt; ++jt) {
        const bool rok = (jt >= 2) || (n > 0);
        const bool base = ck && rok;
        float ev[4];
#pragma unroll
        for (int r = 0; r < 4; ++r) {
          const bool valid = (jt == kt) ? (base && (m16 > g4 + r)) : base;
          ev[r] = valid ? __builtin_amdgcn_exp2f(acc[jt][kt][r]) : 0.f;
          rp[jt * 4 + r] += ev[r];
        }
        qp[kt] += (ev[0] + ev[1]) + (ev[2] + ev[3]);  // tree: 1 chained add
      }
    }

    float rsel, qsel, tp;
    if (n == 0 && i == 0) {
      rsel = 1.f; qsel = 1.f; tp = 64.f;   // degenerate: uniform over 4096
    } else {
      float tin = (qp[0] + qp[1]) + (qp[2] + qp[3]);
#pragma unroll
      for (int off = 1; off <= 32; off <<= 1) tin += __shfl_xor(tin, off);
      tp = tin;

      // reduce-scatter rp[16] -> rsel (kept index == m16)
      float v8[8];
      {
        const bool b = (m16 & 1) != 0;
#pragma unroll
        for (int t2 = 0; t2 < 8; ++t2) {
          const float keep = b ? rp[2 * t2 + 1] : rp[2 * t2];
          const float send = b ? rp[2 * t2] : rp[2 * t2 + 1];
          v8[t2] = keep + __shfl_xor(send, 1);
        }
      }
      float v4s[4];
      {
        const bool b = (m16 & 2) != 0;
#pragma unroll
        for (int t2 = 0; t2 < 4; ++t2) {
          const float keep = b ? v8[2 * t2 + 1] : v8[2 * t2];
          const float send = b ? v8[2 * t2] : v8[2 * t2 + 1];
          v4s[t2] = keep + __shfl_xor(send, 2);
        }
      }
      float v2s[2];
      {
        const bool b = (m16 & 4) != 0;
#pragma unroll
        for (int t2 = 0; t2 < 2; ++t2) {
          const float keep = b ? v4s[2 * t2 + 1] : v4s[2 * t2];
          const float send = b ? v4s[2 * t2] : v4s[2 * t2 + 1];
          v2s[t2] = keep + __shfl_xor(send, 4);
        }
      }
      {
        const bool b = (m16 & 8) != 0;
        const float keep = b ? v2s[1] : v2s[0];
        const float send = b ? v2s[0] : v2s[1];
        rsel = keep + __shfl_xor(send, 8);
      }
      // reduce-scatter qp[4] -> qsel (kept index == g)
      float q2[2];
      {
        const bool b = (g & 1) != 0;
#pragma unroll
        for (int t2 = 0; t2 < 2; ++t2) {
          const float keep = b ? qp[2 * t2 + 1] : qp[2 * t2];
          const float send = b ? qp[2 * t2] : qp[2 * t2 + 1];
          q2[t2] = keep + __shfl_xor(send, 16);
        }
      }
      {
        const bool b = (g & 2) != 0;
        const float keep = b ? q2[1] : q2[0];
        const float send = b ? q2[0] : q2[1];
        qsel = keep + __shfl_xor(send, 32);
      }
    }

    RQ[i][(m16 >> 2) * 16 + g4 + (m16 & 3)] = f2bf(rsel);
    RQ[i][64 + g * 16 + m16] = f2bf(qsel);
    if (lane == 0) tot_lds[i] = tp;
  }

  __syncthreads();

  // ---- final GEMM: Z[32][64] = [R|Q] @ [D;E]; wave (mt=wv>>2, nt=wv&3)
  const int mt = wv >> 2;
  const int nt = wv & 3;
  f32x4 zac = {0.f, 0.f, 0.f, 0.f};
#pragma unroll
  for (int kq = 0; kq < 4; ++kq) {
    const bf16x8 bf = *reinterpret_cast<const bf16x8*>(&DET[nt * 16 + m16][kq * 32 + g * 8]);
    const bf16x8 af = *reinterpret_cast<const bf16x8*>(&RQ[mt * 16 + m16][kq * 32 + g * 8]);
    zac = __builtin_amdgcn_mfma_f32_16x16x32_bf16(af, bf, zac, 0, 0, 0);
  }
#pragma unroll
  for (int r = 0; r < 4; ++r) {
    const int i = mt * 16 + g4 + r;
    const int d = nt * 16 + m16;
    const float inv = __builtin_amdgcn_rcpf(tot_lds[i]);
    Z[((size_t)bi * SEQL + n * WIN + i) * (NH * DH) + h * DH + d] =
        f2bf(zac[r] * inv);
  }
}

// ---------------------------------------------------------------------------
extern "C" void kernel_launch(void* const* d_in, const int* in_sizes, int n_in,
                              void* d_out, int out_size, void* d_ws, size_t ws_size,
                              hipStream_t stream) {
  const float* x        = (const float*)d_in[0];
  const float* W_abcde  = (const float*)d_in[1];
  const float* b_abcde  = (const float*)d_in[2];
  const float* W_O      = (const float*)d_in[3];
  const float* b_O      = (const float*)d_in[4];
  float* out = (float*)d_out;

  const int M = BSZ * SEQL;  // 2048

  u16* Yb  = (u16*)d_ws;                          // [2048][3840] bf16
  u16* xb  = Yb  + (size_t)M * NCOL;              // [2048][768]
  u16* Wt  = xb  + (size_t)M * DMODEL;            // [3840][768]
  u16* WOt = Wt  + (size_t)NCOL * DMODEL;         // [768][768]
  u16* Zb  = WOt + (size_t)(NH * DH) * DMODEL;    // [2048][768]

  prep_kernel<<<2400, 256, 0, stream>>>(x, W_abcde, W_O, xb, Wt, WOt);

  gemm_mfma_kernel<128, 128, 2, 2, true><<<dim3(NCOL / 128, M / 128), 256, 0, stream>>>(
      xb, Wt, b_abcde, Yb, M, NCOL, DMODEL);

  attn_mfma_kernel<<<dim3(NW, BSZ * NH), 512, 0, stream>>>(Yb, Zb);

  gemm_mfma_kernel<64, 64, 2, 2, false><<<dim3((NH * DH) / 64, M / 64), 256, 0, stream>>>(
      Zb, WOt, b_O, out, M, DMODEL, NH * DH);
}

// Round 7
// 140.013 us; speedup vs baseline: 1.0741x; 1.0741x over previous
//
#include <hip/hip_runtime.h>
#include <math.h>
#include <stdint.h>

#define NH     12
#define DH     64
#define WIN    32
#define SEQL   1024
#define BSZ    2
#define NW     (SEQL / WIN)       // 32
#define DMODEL 768
#define NCOL   (5 * NH * DH)      // 3840

typedef __attribute__((ext_vector_type(4))) float f32x4;
typedef __attribute__((ext_vector_type(8))) _Float16 f16x8;
typedef unsigned short u16;

static __device__ __forceinline__ u16 f2h(float f) {
  union { _Float16 h; u16 u; } v; v.h = (_Float16)f;
  return v.u;
}

typedef const __attribute__((address_space(1))) unsigned int* as1_cu32;
typedef __attribute__((address_space(3))) unsigned int* as3_u32;
static __device__ __forceinline__ void gload_lds16(const void* g, void* l) {
  __builtin_amdgcn_global_load_lds(
      reinterpret_cast<as1_cu32>(reinterpret_cast<uintptr_t>(g)),
      reinterpret_cast<as3_u32>(reinterpret_cast<uintptr_t>(l)), 16, 0, 0);
}

// ---------------------------------------------------------------------------
// Fused prep (fp16): [0,1536) cvt x; [1536,2256) transpose W_abcde;
// [2256,2400) transpose W_O.
// ---------------------------------------------------------------------------
__global__ __launch_bounds__(256)
void prep_kernel(const float* __restrict__ x, const float* __restrict__ W,
                 const float* __restrict__ WO, u16* __restrict__ xb,
                 u16* __restrict__ Wt, u16* __restrict__ WOt) {
  __shared__ u16 tile[64][68];
  const int bid = blockIdx.x;
  const int tid = threadIdx.x;

  if (bid < 1536) {                      // ---- cvt x (2048*768 elems, x4)
    const int i = bid * 256 + tid;
    const float4 v = reinterpret_cast<const float4*>(x)[i];
    ushort4 o;
    o.x = f2h(v.x); o.y = f2h(v.y); o.z = f2h(v.z); o.w = f2h(v.w);
    reinterpret_cast<ushort4*>(xb)[i] = o;
    return;
  }

  const float* S; u16* D; int K, N, n0, k0;
  if (bid < 2256) {                      // ---- W_abcde [768][3840] -> [3840][768]
    const int b = bid - 1536;
    S = W; D = Wt; K = DMODEL; N = NCOL;
    n0 = (b % 60) * 64; k0 = (b / 60) * 64;
  } else {                               // ---- W_O [768][768] -> [768][768]
    const int b = bid - 2256;
    S = WO; D = WOt; K = DMODEL; N = NH * DH;
    n0 = (b % 12) * 64; k0 = (b / 12) * 64;
  }
#pragma unroll
  for (int pass = 0; pass < 4; ++pass) {
    const int r = pass * 16 + (tid >> 4);
    const int c = (tid & 15) << 2;
    const float4 v = *reinterpret_cast<const float4*>(&S[(size_t)(k0 + r) * N + n0 + c]);
    tile[c + 0][r] = f2h(v.x); tile[c + 1][r] = f2h(v.y);
    tile[c + 2][r] = f2h(v.z); tile[c + 3][r] = f2h(v.w);
  }
  __syncthreads();
#pragma unroll
  for (int pass = 0; pass < 4; ++pass) {
    const int rn = pass * 16 + (tid >> 4);
    const int ck = (tid & 15) << 2;
    ushort4 o;
    o.x = tile[rn][ck + 0]; o.y = tile[rn][ck + 1];
    o.z = tile[rn][ck + 2]; o.w = tile[rn][ck + 3];
    *reinterpret_cast<ushort4*>(&D[(size_t)(n0 + rn) * K + k0 + ck]) = o;
  }
}

// ---------------------------------------------------------------------------
// fp16 MFMA GEMM, 2-phase double-buffered. OUT_MODE: 0=f32, 1=f16.
// ---------------------------------------------------------------------------
template<int BM, int BN, int WAVES_M, int WAVES_N, int OUT_MODE>
__global__ __launch_bounds__(256)
void gemm_mfma_kernel(const u16* __restrict__ A, const u16* __restrict__ Bt,
                      const float* __restrict__ bias, void* __restrict__ Cout,
                      int M, int N, int K) {
  constexpr int BK = 64;
  constexpr int MT = BM / (16 * WAVES_M);
  constexpr int NT = BN / (16 * WAVES_N);
  constexpr int CHA = BM / 8;
  constexpr int CHB = BN / 8;
  __shared__ __align__(16) u16 As[2][BM * BK];
  __shared__ __align__(16) u16 Bs[2][BN * BK];

  const int tid  = threadIdx.x;
  const int w    = tid >> 6;
  const int lane = tid & 63;
  const int m16  = lane & 15;
  const int g    = lane >> 4;
  const int wr   = w / WAVES_N;
  const int wc   = w % WAVES_N;
  const int bm   = blockIdx.y * BM;
  const int bn   = blockIdx.x * BN;

  const int srow   = lane >> 3;
  const int srcCol = ((lane & 7) ^ srow) << 3;

  auto stage = [&](int buf, int k0) {
#pragma unroll
    for (int c = 0; c < CHA / 4; ++c) {
      const int ch = w * (CHA / 4) + c;
      const int r  = ch * 8 + srow;
      gload_lds16(A + (size_t)(bm + r) * K + k0 + srcCol, &As[buf][ch * 512]);
    }
#pragma unroll
    for (int c = 0; c < CHB / 4; ++c) {
      const int ch = w * (CHB / 4) + c;
      const int r  = ch * 8 + srow;
      gload_lds16(Bt + (size_t)(bn + r) * K + k0 + srcCol, &Bs[buf][ch * 512]);
    }
  };

  f32x4 acc[MT][NT];
#pragma unroll
  for (int i = 0; i < MT; ++i)
#pragma unroll
    for (int j = 0; j < NT; ++j) {
      f32x4 z = {0.f, 0.f, 0.f, 0.f};
      acc[i][j] = z;
    }

  stage(0, 0);
  __syncthreads();

  int cur = 0;
  for (int k0 = 0; k0 < K; k0 += BK) {
    const int nk = k0 + BK;
    if (nk < K) stage(cur ^ 1, nk);

#pragma unroll
    for (int kk = 0; kk < 2; ++kk) {
      const int cs = (((kk << 2) + g) ^ (m16 & 7)) << 3;
      f16x8 af[MT], bf[NT];
#pragma unroll
      for (int i = 0; i < MT; ++i) {
        const int r = wr * (16 * MT) + i * 16 + m16;
        af[i] = *reinterpret_cast<const f16x8*>(&As[cur][r * 64 + cs]);
      }
#pragma unroll
      for (int j = 0; j < NT; ++j) {
        const int r = wc * (16 * NT) + j * 16 + m16;
        bf[j] = *reinterpret_cast<const f16x8*>(&Bs[cur][r * 64 + cs]);
      }
#pragma unroll
      for (int i = 0; i < MT; ++i)
#pragma unroll
        for (int j = 0; j < NT; ++j)
          acc[i][j] = __builtin_amdgcn_mfma_f32_16x16x32_f16(af[i], bf[j], acc[i][j], 0, 0, 0);
    }
    __syncthreads();
    cur ^= 1;
  }

#pragma unroll
  for (int i = 0; i < MT; ++i) {
#pragma unroll
    for (int j = 0; j < NT; ++j) {
      const int col = bn + wc * 16 * NT + j * 16 + m16;
      const float bcol = bias[col];
#pragma unroll
      for (int rr = 0; rr < 4; ++rr) {
        const int row = bm + wr * 16 * MT + i * 16 + g * 4 + rr;
        const float v = acc[i][j][rr] + bcol;
        if (OUT_MODE == 1)
          reinterpret_cast<u16*>(Cout)[(size_t)row * N + col] = f2h(v);
        else
          reinterpret_cast<float*>(Cout)[(size_t)row * N + col] = v;
      }
    }
  }
}

// ---------------------------------------------------------------------------
// MFMA trittention v5: full fp16. vf = pk_mul(c*K2, b) — zero conversions in
// the hot loop. Triangle tiles only; reduce-scatter marginals; no max-sub.
// ---------------------------------------------------------------------------
__global__ __launch_bounds__(512, 3)
void attn_mfma_kernel(const u16* __restrict__ Y, u16* __restrict__ Z) {
  __shared__ __align__(16) u16 DET[64][136];  // [d][0..63]=D^T, [64..127]=E^T
  __shared__ __align__(16) u16 RQ[32][136];   // [i][0..63]=r[j], [64..127]=q[k]
  __shared__ float tot_lds[32];

  const int n  = blockIdx.x;
  const int bh = blockIdx.y;
  const int bi = bh / NH;
  const int h  = bh % NH;
  const int tid  = threadIdx.x;
  const int wv   = tid >> 6;      // 0..7
  const int lane = tid & 63;
  const int m16  = lane & 15;
  const int g    = lane >> 4;
  const int g4   = g << 2;
  const u16* Yb = Y + (size_t)bi * SEQL * NCOL;

  // ---- stage D^T / E^T: wave wv writes dims [wv*8, wv*8+8), lane = j
  {
    const int j  = lane;
    const int r8 = wv * 8;
    const int t  = n * WIN - WIN + j;
    if (t >= 0) {
      const f16x8 dv = *reinterpret_cast<const f16x8*>(
          Yb + (size_t)t * NCOL + (3 * NH + h) * DH + r8);
      const f16x8 ev = *reinterpret_cast<const f16x8*>(
          Yb + (size_t)t * NCOL + (4 * NH + h) * DH + r8);
#pragma unroll
      for (int e = 0; e < 8; ++e) {
        union { _Float16 h; u16 u; } cd, ce;
        cd.h = dv[e]; ce.h = ev[e];
        DET[r8 + e][j]      = cd.u;
        DET[r8 + e][64 + j] = ce.u;
      }
    } else {
#pragma unroll
      for (int e = 0; e < 8; ++e) {
        DET[r8 + e][j] = 0;
        DET[r8 + e][64 + j] = 0;
      }
    }
  }

  // ---- preload A-fragments and b rows (fp16 regs)
  f16x8 afr[4][2], bfrb[4][2];
#pragma unroll
  for (int jt = 0; jt < 4; ++jt) {
    const int t = n * WIN - WIN + jt * 16 + m16;
#pragma unroll
    for (int ks = 0; ks < 2; ++ks) {
      if (n == 0 && jt < 2) {
        f16x8 z = {0, 0, 0, 0, 0, 0, 0, 0};
        afr[jt][ks] = z;
        bfrb[jt][ks] = z;
      } else {
        afr[jt][ks] = *reinterpret_cast<const f16x8*>(
            Yb + (size_t)t * NCOL + h * DH + ks * 32 + g * 8);
        bfrb[jt][ks] = *reinterpret_cast<const f16x8*>(
            Yb + (size_t)t * NCOL + (NH + h) * DH + ks * 32 + g * 8);
      }
    }
  }

  const float K2 = 0.015625f * 1.44269504088896341f;  // log2(e)/64
  const _Float16 K2h = (_Float16)K2;
  const u16* crow_base = Yb + (size_t)(n * WIN) * NCOL + (2 * NH + h) * DH;

  // prefetch first query's c-row
  f16x8 craw0 = *reinterpret_cast<const f16x8*>(
      crow_base + (size_t)(wv * 4) * NCOL + g * 8);
  f16x8 craw1 = *reinterpret_cast<const f16x8*>(
      crow_base + (size_t)(wv * 4) * NCOL + 32 + g * 8);

  for (int ii = 0; ii < 4; ++ii) {
    const int i = wv * 4 + ii;

    // cf = c * K2 (fp16 packed, 8 pk_mul)
    f16x8 cfh[2];
#pragma unroll
    for (int e = 0; e < 8; ++e) {
      cfh[0][e] = craw0[e] * K2h;
      cfh[1][e] = craw1[e] * K2h;
    }
    // issue next query's c-row load early
    if (ii < 3) {
      const u16* cpn = crow_base + (size_t)(i + 1) * NCOL;
      craw0 = *reinterpret_cast<const f16x8*>(cpn + g * 8);
      craw1 = *reinterpret_cast<const f16x8*>(cpn + 32 + g * 8);
    }

    f32x4 acc[4][4];
#pragma unroll
    for (int kt = 0; kt < 4; ++kt)
#pragma unroll
      for (int jt = 0; jt <= kt; ++jt) {
        f32x4 z = {0.f, 0.f, 0.f, 0.f};
        acc[jt][kt] = z;
      }

    // S_i*K2 = A @ (c_i*K2 * B)^T : jt<=kt tiles (20 MFMAs, 4 pk_mul/tile)
#pragma unroll
    for (int ks = 0; ks < 2; ++ks) {
#pragma unroll
      for (int kt = 0; kt < 4; ++kt) {
        const f16x8 vf = cfh[ks] * bfrb[kt][ks];
#pragma unroll
        for (int jt = 0; jt <= kt; ++jt)
          acc[jt][kt] = __builtin_amdgcn_mfma_f32_16x16x32_f16(afr[jt][ks], vf, acc[jt][kt], 0, 0, 0);
      }
    }

    // ---- exp + masked marginal partials (upper-triangle tiles only)
    float rp[16], qp[4];
#pragma unroll
    for (int u = 0; u < 16; ++u) rp[u] = 0.f;
#pragma unroll
    for (int u = 0; u < 4; ++u) qp[u] = 0.f;
#pragma unroll
    for (int kt = 0; kt < 4; ++kt) {
      const bool ck = (kt < 2) ? true : (kt * 16 + m16 <= i + 32);
#pragma unroll
      for (int jt = 0; jt <= kt; ++jt) {
        const bool rok = (jt >= 2) || (n > 0);
        const bool base = ck && rok;
        float ev[4];
#pragma unroll
        for (int r = 0; r < 4; ++r) {
          const bool valid = (jt == kt) ? (base && (m16 > g4 + r)) : base;
          ev[r] = valid ? __builtin_amdgcn_exp2f(acc[jt][kt][r]) : 0.f;
          rp[jt * 4 + r] += ev[r];
        }
        qp[kt] += (ev[0] + ev[1]) + (ev[2] + ev[3]);
      }
    }

    float rsel, qsel, tp;
    if (n == 0 && i == 0) {
      rsel = 1.f; qsel = 1.f; tp = 64.f;   // degenerate: uniform over 4096
    } else {
      float tin = (qp[0] + qp[1]) + (qp[2] + qp[3]);
#pragma unroll
      for (int off = 1; off <= 32; off <<= 1) tin += __shfl_xor(tin, off);
      tp = tin;

      // reduce-scatter rp[16] -> rsel (kept index == m16)
      float v8[8];
      {
        const bool b = (m16 & 1) != 0;
#pragma unroll
        for (int t2 = 0; t2 < 8; ++t2) {
          const float keep = b ? rp[2 * t2 + 1] : rp[2 * t2];
          const float send = b ? rp[2 * t2] : rp[2 * t2 + 1];
          v8[t2] = keep + __shfl_xor(send, 1);
        }
      }
      float v4s[4];
      {
        const bool b = (m16 & 2) != 0;
#pragma unroll
        for (int t2 = 0; t2 < 4; ++t2) {
          const float keep = b ? v8[2 * t2 + 1] : v8[2 * t2];
          const float send = b ? v8[2 * t2] : v8[2 * t2 + 1];
          v4s[t2] = keep + __shfl_xor(send, 2);
        }
      }
      float v2s[2];
      {
        const bool b = (m16 & 4) != 0;
#pragma unroll
        for (int t2 = 0; t2 < 2; ++t2) {
          const float keep = b ? v4s[2 * t2 + 1] : v4s[2 * t2];
          const float send = b ? v4s[2 * t2] : v4s[2 * t2 + 1];
          v2s[t2] = keep + __shfl_xor(send, 4);
        }
      }
      {
        const bool b = (m16 & 8) != 0;
        const float keep = b ? v2s[1] : v2s[0];
        const float send = b ? v2s[0] : v2s[1];
        rsel = keep + __shfl_xor(send, 8);
      }
      // reduce-scatter qp[4] -> qsel (kept index == g)
      float q2[2];
      {
        const bool b = (g & 1) != 0;
#pragma unroll
        for (int t2 = 0; t2 < 2; ++t2) {
          const float keep = b ? qp[2 * t2 + 1] : qp[2 * t2];
          const float send = b ? qp[2 * t2] : qp[2 * t2 + 1];
          q2[t2] = keep + __shfl_xor(send, 16);
        }
      }
      {
        const bool b = (g & 2) != 0;
        const float keep = b ? q2[1] : q2[0];
        const float send = b ? q2[0] : q2[1];
        qsel = keep + __shfl_xor(send, 32);
      }
    }

    RQ[i][(m16 >> 2) * 16 + g4 + (m16 & 3)] = f2h(rsel);
    RQ[i][64 + g * 16 + m16] = f2h(qsel);
    if (lane == 0) tot_lds[i] = tp;
  }

  __syncthreads();

  // ---- final GEMM: Z[32][64] = [R|Q] @ [D;E]; wave (mt=wv>>2, nt=wv&3)
  const int mt = wv >> 2;
  const int nt = wv & 3;
  f32x4 zac = {0.f, 0.f, 0.f, 0.f};
#pragma unroll
  for (int kq = 0; kq < 4; ++kq) {
    const f16x8 bf = *reinterpret_cast<const f16x8*>(&DET[nt * 16 + m16][kq * 32 + g * 8]);
    const f16x8 af = *reinterpret_cast<const f16x8*>(&RQ[mt * 16 + m16][kq * 32 + g * 8]);
    zac = __builtin_amdgcn_mfma_f32_16x16x32_f16(af, bf, zac, 0, 0, 0);
  }
#pragma unroll
  for (int r = 0; r < 4; ++r) {
    const int i = mt * 16 + g4 + r;
    const int d = nt * 16 + m16;
    const float inv = __builtin_amdgcn_rcpf(tot_lds[i]);
    Z[((size_t)bi * SEQL + n * WIN + i) * (NH * DH) + h * DH + d] =
        f2h(zac[r] * inv);
  }
}

// ---------------------------------------------------------------------------
extern "C" void kernel_launch(void* const* d_in, const int* in_sizes, int n_in,
                              void* d_out, int out_size, void* d_ws, size_t ws_size,
                              hipStream_t stream) {
  const float* x        = (const float*)d_in[0];
  const float* W_abcde  = (const float*)d_in[1];
  const float* b_abcde  = (const float*)d_in[2];
  const float* W_O      = (const float*)d_in[3];
  const float* b_O      = (const float*)d_in[4];
  float* out = (float*)d_out;

  const int M = BSZ * SEQL;  // 2048

  u16* Yb  = (u16*)d_ws;                          // [2048][3840] fp16
  u16* xb  = Yb  + (size_t)M * NCOL;              // [2048][768]
  u16* Wt  = xb  + (size_t)M * DMODEL;            // [3840][768]
  u16* WOt = Wt  + (size_t)NCOL * DMODEL;         // [768][768]
  u16* Zb  = WOt + (size_t)(NH * DH) * DMODEL;    // [2048][768]

  prep_kernel<<<2400, 256, 0, stream>>>(x, W_abcde, W_O, xb, Wt, WOt);

  gemm_mfma_kernel<128, 128, 2, 2, 1><<<dim3(NCOL / 128, M / 128), 256, 0, stream>>>(
      xb, Wt, b_abcde, Yb, M, NCOL, DMODEL);

  attn_mfma_kernel<<<dim3(NW, BSZ * NH), 512, 0, stream>>>(Yb, Zb);

  gemm_mfma_kernel<64, 64, 2, 2, 0><<<dim3((NH * DH) / 64, M / 64), 256, 0, stream>>>(
      Zb, WOt, b_O, out, M, DMODEL, NH * DH);
}